// Round 3
// baseline (199.612 us; speedup 1.0000x reference)
//
#include <hip/hip_runtime.h>
#include <hip/hip_bf16.h>

// Conv2D 3x3 pad1 stride1: x(32,32,128,128) fp32 * w(64,32,3,3) + bias -> (32,64,128,128) fp32
// bf16 MFMA implicit GEMM.
// Round 3: 512-thread block = one (batch n, output row PAIR h0,h0+1). Stages 4 x
// rows (h0-1..h0+2) once; waves 0-3 compute row h0, waves 4-7 row h0+1. Cuts
// staging VALU per output row 3x and x request traffic 1.5x vs 1-row blocks.
// Weights pre-packed to A-frag order in d_ws (repack_w) and read from L2.

typedef __attribute__((ext_vector_type(8))) short bf16x8;
typedef __attribute__((ext_vector_type(4))) float f32x4;

#define NB 32
#define CIN 32
#define HH 128
#define WW 128
#define NK 64
#define XROW (130 * 32)   // one LDS x row: wi 0..129 (w halo), c 0..31

__device__ __forceinline__ unsigned short f2bf(float f) {
    union { float f; unsigned int u; } v; v.f = f;
    unsigned int u = v.u;
    return (unsigned short)((u + 0x7FFFu + ((u >> 16) & 1u)) >> 16);  // RNE
}

// LDS x element: [wi][c] bf16, 16B-chunk XOR swizzle spreads banks for the
// b32 transpose writes and keeps b128 frag reads uniform.
__device__ __forceinline__ int xel(int wi, int c) {
    return wi * 32 + ((((c >> 3) ^ ((wi >> 2) & 3)) << 3) | (c & 7));
}

// Pre-kernel: kern[ok][c*9+kidx] fp32 -> wfrag bf16 in A-fragment order:
// wfrag[((kidx*4 + tile)*64 + lane)*8 + j], ok = tile*16 + (lane&15), c = (lane>>4)*8 + j.
__global__ void repack_w(const float* __restrict__ kern,
                         unsigned short* __restrict__ wfrag) {
    int u = blockIdx.x * 256 + threadIdx.x;      // 0..18431
    int j = u & 7;
    int lane = (u >> 3) & 63;
    int tile = (u >> 9) & 3;
    int kidx = u >> 11;
    int ok = tile * 16 + (lane & 15);
    int c = ((lane >> 4) << 3) + j;
    wfrag[u] = f2bf(kern[ok * 288 + c * 9 + kidx]);
}

__global__ __launch_bounds__(512, 6) void conv3x3_mfma(
        const float* __restrict__ x, const unsigned short* __restrict__ wfrag,
        const float* __restrict__ bias, float* __restrict__ out) {
    __shared__ unsigned short lds_x[4 * XROW];   // 33280 B

    const int tid = threadIdx.x;
    const int bx = blockIdx.x;                   // 0..63 (h pairs)
    // XCD swizzle: XCD i gets h-pair range [8i, 8i+8) -> h in [16i,16i+16);
    // h-adjacent blocks (sharing 2 of 4 x rows) hit the same XCD's L2.
    const int hp = ((bx & 7) << 3) | (bx >> 3);
    const int h0 = hp * 2;
    const int n = blockIdx.y;
    const int lane = tid & 63;
    const int l16 = lane & 15;
    const int q = lane >> 4;            // 0..3
    const int wav = tid >> 6;           // 0..7
    const int hsel = wav >> 2;          // 0: row h0, 1: row h0+1
    const int sub = wav & 3;
    const int ok_tile = (sub & 1) * 2;  // A-frag tiles ok_tile, ok_tile+1
    const int w_base = (sub >> 1) * 64; // wave covers w w_base..+63

    // halo zeros (wi=0 -> w=-1, wi=129 -> w=128) for all 4 row buffers
    if (tid < 256) {
        int it = tid >> 6;
        int idx = tid & 63;
        int c = idx & 31;
        int wi = (idx < 32) ? 0 : 129;
        lds_x[it * XROW + xel(wi, c)] = 0;
    }

    // ---- stage rows h0-1 .. h0+2 transposed [w][c] fp32->bf16 ----
    {
        const int c = (tid >> 5) * 2;            // even channel 0..30
        const int wq = tid & 31;                 // float4 index along w
        #pragma unroll
        for (int it = 0; it < 4; ++it) {
            const int r = h0 - 1 + it;
            const bool valid = (unsigned)r < HH;
            float4 va = {0.f, 0.f, 0.f, 0.f}, vb = {0.f, 0.f, 0.f, 0.f};
            if (valid) {
                const float* xrow = x + (((size_t)n * CIN + c) * HH + r) * WW;
                va = *((const float4*)xrow + wq);
                vb = *((const float4*)(xrow + (size_t)HH * WW) + wq);
            }
            unsigned short* lrow = lds_x + it * XROW;
            #pragma unroll
            for (int j = 0; j < 4; ++j) {
                int w = wq * 4 + j;
                __hip_bfloat162 h2 = __float22bfloat162_rn(
                    make_float2((&va.x)[j], (&vb.x)[j]));
                *(unsigned int*)&lrow[xel(w + 1, c)] = *(unsigned int*)&h2;  // c even -> 4B aligned
            }
        }
    }
    __syncthreads();

    f32x4 acc[2][4];
    #pragma unroll
    for (int mi = 0; mi < 2; ++mi)
        #pragma unroll
        for (int ni = 0; ni < 4; ++ni)
            acc[mi][ni] = (f32x4){0.f, 0.f, 0.f, 0.f};

    #pragma unroll 1   // keep VGPR pressure down
    for (int kr = 0; kr < 3; ++kr) {
        const unsigned short* lrow = lds_x + (hsel + kr) * XROW;
        #pragma unroll
        for (int kc = 0; kc < 3; ++kc) {
            const int kidx = kr * 3 + kc;
            bf16x8 afr[2];
            #pragma unroll
            for (int mi = 0; mi < 2; ++mi)
                afr[mi] = *(const bf16x8*)
                    &wfrag[(size_t)(((kidx * 4) + ok_tile + mi) * 64 + lane) * 8];
            #pragma unroll
            for (int ni = 0; ni < 4; ++ni) {
                bf16x8 bfr = *(const bf16x8*)&lrow[xel(w_base + ni * 16 + l16 + kc, q * 8)];
                #pragma unroll
                for (int mi = 0; mi < 2; ++mi)
                    acc[mi][ni] = __builtin_amdgcn_mfma_f32_16x16x32_bf16(
                        afr[mi], bfr, acc[mi][ni], 0, 0, 0);
            }
        }
    }

    // ---- epilogue: + bias, coalesced stores (16 consecutive w per 16-lane group) ----
    const int h = h0 + hsel;
    #pragma unroll
    for (int mi = 0; mi < 2; ++mi) {
        #pragma unroll
        for (int rg = 0; rg < 4; ++rg) {
            int ok = (sub & 1) * 32 + mi * 16 + q * 4 + rg;
            float bv = bias[ok];
            float* orow = out + (((size_t)n * NK + ok) * HH + h) * WW;
            #pragma unroll
            for (int ni = 0; ni < 4; ++ni)
                orow[w_base + ni * 16 + l16] = acc[mi][ni][rg] + bv;
        }
    }
}

extern "C" void kernel_launch(void* const* d_in, const int* in_sizes, int n_in,
                              void* d_out, int out_size, void* d_ws, size_t ws_size,
                              hipStream_t stream) {
    const float* x    = (const float*)d_in[0];
    const float* kern = (const float*)d_in[1];
    const float* bias = (const float*)d_in[2];
    float* out = (float*)d_out;
    unsigned short* wfrag = (unsigned short*)d_ws;   // 18432 bf16 = 36864 B

    repack_w<<<72, 256, 0, stream>>>(kern, wfrag);
    dim3 grid(64, NB);  // (swizzled h-pair, batch)
    conv3x3_mfma<<<grid, 512, 0, stream>>>(x, wfrag, bias, out);
}

// Round 4
// 192.902 us; speedup vs baseline: 1.0348x; 1.0348x over previous
//
#include <hip/hip_runtime.h>
#include <hip/hip_bf16.h>

// Conv2D 3x3 pad1 stride1: x(32,32,128,128) fp32 * w(64,32,3,3) + bias -> (32,64,128,128) fp32
// bf16 MFMA implicit GEMM.
// Round 4: 512-thread block = (batch n, 4 output rows h0..h0+3). 6-row LDS
// window; rows h0-1..h0+2 staged up front, rows h0+3/h0+4 prefetched to VGPRs
// before the first barrier and written to LDS after step-0 compute (latency
// hidden behind MFMA). Step 0 computes h0,h0+1; step 1 computes h0+2,h0+3.
// x request traffic: 1.5 input rows per output row (was 2 in R3, 3 in R1).
// Weights pre-packed to A-frag order in d_ws (repack_w), read via L2.

typedef __attribute__((ext_vector_type(8))) short bf16x8;
typedef __attribute__((ext_vector_type(4))) float f32x4;

#define NB 32
#define CIN 32
#define HH 128
#define WW 128
#define NK 64
#define XROW (130 * 32)   // one LDS x row: wi 0..129 (w halo), c 0..31

__device__ __forceinline__ unsigned short f2bf(float f) {
    union { float f; unsigned int u; } v; v.f = f;
    unsigned int u = v.u;
    return (unsigned short)((u + 0x7FFFu + ((u >> 16) & 1u)) >> 16);  // RNE
}

// LDS x element: [wi][c] bf16, 16B-chunk XOR swizzle spreads banks for the
// b32 transpose writes and keeps b128 frag reads uniform.
__device__ __forceinline__ int xel(int wi, int c) {
    return wi * 32 + ((((c >> 3) ^ ((wi >> 2) & 3)) << 3) | (c & 7));
}

// Pre-kernel: kern[ok][c*9+kidx] fp32 -> wfrag bf16 in A-fragment order:
// wfrag[((kidx*4 + tile)*64 + lane)*8 + j], ok = tile*16 + (lane&15), c = (lane>>4)*8 + j.
__global__ void repack_w(const float* __restrict__ kern,
                         unsigned short* __restrict__ wfrag) {
    int u = blockIdx.x * 256 + threadIdx.x;      // 0..18431
    int j = u & 7;
    int lane = (u >> 3) & 63;
    int tile = (u >> 9) & 3;
    int kidx = u >> 11;
    int ok = tile * 16 + (lane & 15);
    int c = ((lane >> 4) << 3) + j;
    wfrag[u] = f2bf(kern[ok * 288 + c * 9 + kidx]);
}

__global__ __launch_bounds__(512, 4) void conv3x3_mfma(
        const float* __restrict__ x, const unsigned short* __restrict__ wfrag,
        const float* __restrict__ bias, float* __restrict__ out) {
    __shared__ unsigned short lds_x[6 * XROW];   // 49920 B

    const int tid = threadIdx.x;
    const int bx = blockIdx.x;                   // 0..31 (h quads)
    // XCD swizzle: XCD i gets hgroups 4i..4i+3 -> rows 16i..16i+15; adjacent
    // hgroups (sharing boundary x rows) hit the same XCD's L2.
    const int hgroup = ((bx & 7) << 2) | (bx >> 3);
    const int h0 = hgroup * 4;
    const int n = blockIdx.y;
    const int lane = tid & 63;
    const int l16 = lane & 15;
    const int q = lane >> 4;            // 0..3
    const int wav = tid >> 6;           // 0..7
    const int hsel = wav >> 2;          // wave's row within a pair-step
    const int sub = wav & 3;
    const int ok_tile = (sub & 1) * 2;  // A-frag tiles ok_tile, ok_tile+1
    const int w_base = (sub >> 1) * 64; // wave covers w w_base..+63

    // halo zeros (wi=0 -> w=-1, wi=129 -> w=128) for all 6 row buffers
    if (tid < 384) {
        int it = tid >> 6;
        int idx = tid & 63;
        int c = idx & 31;
        int wi = (idx < 32) ? 0 : 129;
        lds_x[it * XROW + xel(wi, c)] = 0;
    }

    const int c = (tid >> 5) * 2;            // even channel 0..30
    const int wq = tid & 31;                 // float4 index along w

    // ---- upfront stage: input rows h0-1 .. h0+2 -> bufs 0..3 ----
    #pragma unroll
    for (int it = 0; it < 4; ++it) {
        const int r = h0 - 1 + it;
        const bool valid = (unsigned)r < HH;
        float4 va = {0.f, 0.f, 0.f, 0.f}, vb = {0.f, 0.f, 0.f, 0.f};
        if (valid) {
            const float* xrow = x + (((size_t)n * CIN + c) * HH + r) * WW;
            va = *((const float4*)xrow + wq);
            vb = *((const float4*)(xrow + (size_t)HH * WW) + wq);
        }
        unsigned short* lrow = lds_x + it * XROW;
        #pragma unroll
        for (int j = 0; j < 4; ++j) {
            int w = wq * 4 + j;
            __hip_bfloat162 h2 = __float22bfloat162_rn(
                make_float2((&va.x)[j], (&vb.x)[j]));
            *(unsigned int*)&lrow[xel(w + 1, c)] = *(unsigned int*)&h2;
        }
    }

    // ---- prefetch rows h0+3, h0+4 into registers (loads in flight across
    //      the barrier and step-0 compute) ----
    float4 p0a, p0b, p1a = {0.f,0.f,0.f,0.f}, p1b = {0.f,0.f,0.f,0.f};
    {
        const float* xr3 = x + (((size_t)n * CIN + c) * HH + (h0 + 3)) * WW;
        p0a = *((const float4*)xr3 + wq);                       // h0+3 always < 128
        p0b = *((const float4*)(xr3 + (size_t)HH * WW) + wq);
        if (h0 + 4 < HH) {
            const float* xr4 = x + (((size_t)n * CIN + c) * HH + (h0 + 4)) * WW;
            p1a = *((const float4*)xr4 + wq);
            p1b = *((const float4*)(xr4 + (size_t)HH * WW) + wq);
        }
    }
    __syncthreads();

    // ---- step 0: compute rows h0+hsel from bufs 0..3 ----
    f32x4 acc0[2][4];
    #pragma unroll
    for (int mi = 0; mi < 2; ++mi)
        #pragma unroll
        for (int ni = 0; ni < 4; ++ni)
            acc0[mi][ni] = (f32x4){0.f, 0.f, 0.f, 0.f};

    #pragma unroll 1
    for (int kr = 0; kr < 3; ++kr) {
        const unsigned short* lrow = lds_x + (hsel + kr) * XROW;
        #pragma unroll
        for (int kc = 0; kc < 3; ++kc) {
            const int kidx = kr * 3 + kc;
            bf16x8 afr[2];
            #pragma unroll
            for (int mi = 0; mi < 2; ++mi)
                afr[mi] = *(const bf16x8*)
                    &wfrag[(size_t)(((kidx * 4) + ok_tile + mi) * 64 + lane) * 8];
            #pragma unroll
            for (int ni = 0; ni < 4; ++ni) {
                bf16x8 bfr = *(const bf16x8*)&lrow[xel(w_base + ni * 16 + l16 + kc, q * 8)];
                #pragma unroll
                for (int mi = 0; mi < 2; ++mi)
                    acc0[mi][ni] = __builtin_amdgcn_mfma_f32_16x16x32_bf16(
                        afr[mi], bfr, acc0[mi][ni], 0, 0, 0);
            }
        }
    }

    // ---- write prefetched rows to bufs 4,5 (not read by step 0) ----
    {
        unsigned short* l4 = lds_x + 4 * XROW;
        unsigned short* l5 = lds_x + 5 * XROW;
        #pragma unroll
        for (int j = 0; j < 4; ++j) {
            int w = wq * 4 + j;
            __hip_bfloat162 h2a = __float22bfloat162_rn(
                make_float2((&p0a.x)[j], (&p0b.x)[j]));
            *(unsigned int*)&l4[xel(w + 1, c)] = *(unsigned int*)&h2a;
            __hip_bfloat162 h2b = __float22bfloat162_rn(
                make_float2((&p1a.x)[j], (&p1b.x)[j]));
            *(unsigned int*)&l5[xel(w + 1, c)] = *(unsigned int*)&h2b;
        }
    }
    __syncthreads();

    // ---- step-0 epilogue after the barrier so the barrier's vmcnt drain
    //      doesn't wait on the stores; they overlap step-1 compute ----
    {
        const int h = h0 + hsel;
        #pragma unroll
        for (int mi = 0; mi < 2; ++mi) {
            #pragma unroll
            for (int rg = 0; rg < 4; ++rg) {
                int ok = (sub & 1) * 32 + mi * 16 + q * 4 + rg;
                float bv = bias[ok];
                float* orow = out + (((size_t)n * NK + ok) * HH + h) * WW;
                #pragma unroll
                for (int ni = 0; ni < 4; ++ni)
                    orow[w_base + ni * 16 + l16] = acc0[mi][ni][rg] + bv;
            }
        }
    }

    // ---- step 1: compute rows h0+2+hsel from bufs 2..5 ----
    f32x4 acc1[2][4];
    #pragma unroll
    for (int mi = 0; mi < 2; ++mi)
        #pragma unroll
        for (int ni = 0; ni < 4; ++ni)
            acc1[mi][ni] = (f32x4){0.f, 0.f, 0.f, 0.f};

    #pragma unroll 1
    for (int kr = 0; kr < 3; ++kr) {
        const unsigned short* lrow = lds_x + (2 + hsel + kr) * XROW;
        #pragma unroll
        for (int kc = 0; kc < 3; ++kc) {
            const int kidx = kr * 3 + kc;
            bf16x8 afr[2];
            #pragma unroll
            for (int mi = 0; mi < 2; ++mi)
                afr[mi] = *(const bf16x8*)
                    &wfrag[(size_t)(((kidx * 4) + ok_tile + mi) * 64 + lane) * 8];
            #pragma unroll
            for (int ni = 0; ni < 4; ++ni) {
                bf16x8 bfr = *(const bf16x8*)&lrow[xel(w_base + ni * 16 + l16 + kc, q * 8)];
                #pragma unroll
                for (int mi = 0; mi < 2; ++mi)
                    acc1[mi][ni] = __builtin_amdgcn_mfma_f32_16x16x32_bf16(
                        afr[mi], bfr, acc1[mi][ni], 0, 0, 0);
            }
        }
    }

    {
        const int h = h0 + 2 + hsel;
        #pragma unroll
        for (int mi = 0; mi < 2; ++mi) {
            #pragma unroll
            for (int rg = 0; rg < 4; ++rg) {
                int ok = (sub & 1) * 32 + mi * 16 + q * 4 + rg;
                float bv = bias[ok];
                float* orow = out + (((size_t)n * NK + ok) * HH + h) * WW;
                #pragma unroll
                for (int ni = 0; ni < 4; ++ni)
                    orow[w_base + ni * 16 + l16] = acc1[mi][ni][rg] + bv;
            }
        }
    }
}

extern "C" void kernel_launch(void* const* d_in, const int* in_sizes, int n_in,
                              void* d_out, int out_size, void* d_ws, size_t ws_size,
                              hipStream_t stream) {
    const float* x    = (const float*)d_in[0];
    const float* kern = (const float*)d_in[1];
    const float* bias = (const float*)d_in[2];
    float* out = (float*)d_out;
    unsigned short* wfrag = (unsigned short*)d_ws;   // 18432 bf16 = 36864 B

    repack_w<<<72, 256, 0, stream>>>(kern, wfrag);
    dim3 grid(32, NB);  // (swizzled h-quad, batch)
    conv3x3_mfma<<<grid, 512, 0, stream>>>(x, wfrag, bias, out);
}